// Round 5
// baseline (177.541 us; speedup 1.0000x reference)
//
#include <hip/hip_runtime.h>
#include <stdint.h>

#define LTOT 20000
#define LPAD 20224   // 158*128 = 79*256
#define DV   4096
#define DH   1024
#define DE   100
#define NB   256

using f32x4 = __attribute__((ext_vector_type(4))) float;
using s16x8 = __attribute__((ext_vector_type(8))) short;
using u32x2 = __attribute__((ext_vector_type(2))) uint32_t;
using u32x4 = __attribute__((ext_vector_type(4))) uint32_t;
using f16x2 = __attribute__((ext_vector_type(2))) _Float16;

static __device__ __forceinline__ short f2bf(float x){
  union{float f; uint32_t u;} v; v.f = x;
  uint32_t r = (v.u + 0x7fffu + ((v.u >> 16) & 1u)) >> 16;
  return (short)r;
}

// pack two f32 -> two bf16 (RTNE)
static __device__ __forceinline__ uint32_t pack2bf(float x, float y){
#if __has_builtin(__builtin_amdgcn_cvt_pk_bf16_f32)
  return __builtin_bit_cast(uint32_t, __builtin_amdgcn_cvt_pk_bf16_f32(x, y));
#else
  return (uint32_t)(uint16_t)f2bf(x) | ((uint32_t)(uint16_t)f2bf(y) << 16);
#endif
}

static __device__ __forceinline__ float dot2acc(f16x2 a, float c){
#if __has_builtin(__builtin_amdgcn_fdot2)
  return __builtin_amdgcn_fdot2(a, a, c, false);
#else
  float x = (float)a[0], y = (float)a[1];
  return __builtin_fmaf(x, x, __builtin_fmaf(y, y, c));
#endif
}

// ---------------------------------------------------------------------------
// Kernel 1 (prep), block ranges:
//   0..157  : label_vecs [20000][100] f32 -> lvT [50][LPAD] half2
//   158..165: W2 [1024][100] -> W2T [100][1024] f32
//   166..169: zero H (1 MB)
//   170..233: Abf = bf16(relu(vfs)) [256][4096]
//   234..489: W1 [4096][1024] f32 -> W1T [1024][4096] bf16 (128x128 LDS tiles)
// ---------------------------------------------------------------------------
__global__ __launch_bounds__(256) void prep_k(const float* __restrict__ lab,
                                              uint32_t* __restrict__ lvT,
                                              const float* __restrict__ W2,
                                              float* __restrict__ W2T,
                                              float* __restrict__ H,
                                              const float* __restrict__ vfs,
                                              uint32_t* __restrict__ Abf,
                                              const float* __restrict__ W1,
                                              uint32_t* __restrict__ W1T){
  __shared__ __align__(16) char smem[128 * 101 * 4];   // 51.7 KB, multi-use
  float* T = (float*)smem;
  short* Ts = (short*)smem;                            // [128][136] for W1T tiles
  int t = threadIdx.x;
  int bx = blockIdx.x;
  if (bx < 158){
    int lbase = bx * 128;
    for (int i = t; i < 128 * 100; i += 256){
      int lloc = i / 100;
      int d = i - lloc * 100;
      int l = lbase + lloc;
      float v = (l < LTOT) ? lab[(size_t)l * DE + d] : 0.f;
      T[lloc * 101 + d] = v;
    }
    __syncthreads();
    int lloc = t & 127;
    int half = t >> 7;
    uint32_t lg = (uint32_t)(lbase + lloc);
    #pragma unroll
    for (int q = 0; q < 25; ++q){
      int d2 = half * 25 + q;
      f16x2 p;
      p[0] = (_Float16)T[lloc * 101 + 2 * d2];
      p[1] = (_Float16)T[lloc * 101 + 2 * d2 + 1];
      lvT[(size_t)d2 * LPAD + lg] = __builtin_bit_cast(uint32_t, p);
    }
  } else if (bx < 166){
    int k0 = (bx - 158) * 128;
    for (int i = t; i < 128 * 100; i += 256){
      int kk = i / 100;
      int d = i - kk * 100;
      T[kk * 101 + d] = W2[(size_t)(k0 + kk) * DE + d];
    }
    __syncthreads();
    for (int i = t; i < 100 * 128; i += 256){
      int d = i >> 7, kk = i & 127;
      W2T[(size_t)d * DH + k0 + kk] = T[kk * 101 + d];
    }
  } else if (bx < 170){
    f32x4 z = {};
    float* p = H + (size_t)(bx - 166) * 65536 + t * 4;
    #pragma unroll 4
    for (int i = 0; i < 64; ++i) *(f32x4*)(p + i * 1024) = z;
  } else if (bx < 234){
    // vfs -> bf16(relu): 64 blocks x 16384 floats
    size_t base = (size_t)(bx - 170) * 16384;
    #pragma unroll 4
    for (int j = 0; j < 16; ++j){
      size_t idx = base + (size_t)(j * 256 + t) * 4;
      f32x4 v = *(const f32x4*)(vfs + idx);
      u32x2 o;
      o[0] = pack2bf(__builtin_fmaxf(v[0], 0.f), __builtin_fmaxf(v[1], 0.f));
      o[1] = pack2bf(__builtin_fmaxf(v[2], 0.f), __builtin_fmaxf(v[3], 0.f));
      *(u32x2*)(Abf + (idx >> 1)) = o;
    }
  } else {
    // W1T bf16 transpose: 256 blocks, tile 128k x 128n; Ts[n][k] pad 136
    int bi = bx - 234;
    int k0 = (bi >> 3) * 128, n0 = (bi & 7) * 128;
    #pragma unroll 4
    for (int j = 0; j < 16; ++j){
      int lin = j * 256 + t;              // 4096 f32x4 slots = 128 rows x 32
      int row = lin >> 5, c4 = lin & 31;
      f32x4 v = *(const f32x4*)(W1 + (size_t)(k0 + row) * DH + n0 + c4 * 4);
      #pragma unroll
      for (int i = 0; i < 4; ++i)
        Ts[(c4 * 4 + i) * 136 + row] = f2bf(v[i]);
    }
    __syncthreads();
    #pragma unroll
    for (int j = 0; j < 8; ++j){
      int lin = j * 256 + t;              // 2048 16B-chunks = 128 n x 16
      int nn = lin >> 4, c8 = lin & 15;
      u32x4 o = *(const u32x4*)&Ts[nn * 136 + c8 * 8];
      *(u32x4*)(W1T + ((size_t)(n0 + nn) * DV + k0 + c8 * 8) / 2) = o;
    }
  }
}

// ---------------------------------------------------------------------------
// Kernel 2: H += Abf @ W1T^T  (bf16 MFMA, 64x64 tiles, split-K=8, atomics)
// grid = 4(mt)*16(nt)*8(kt) = 512 blocks (2/CU), 256 thr; pure-copy staging
// ---------------------------------------------------------------------------
__global__ __launch_bounds__(256) void gemm1(const uint32_t* __restrict__ Abf,
                                             const uint32_t* __restrict__ W1T,
                                             float* __restrict__ H){
  __shared__ __align__(16) short Als[64 * 40];  // [m][k] bf16, pad 40
  __shared__ __align__(16) short Bls[64 * 40];  // [n][k] bf16, pad 40
  int t = threadIdx.x;
  int bx = blockIdx.x;
  int kt = bx & 7, nt = (bx >> 3) & 15, mt = bx >> 7;
  int lane = t & 63, wv = t >> 6;
  int wm = wv >> 1, wn = wv & 1;
  int col = lane & 15, quad = lane >> 4;

  f32x4 acc00 = {}, acc01 = {}, acc10 = {}, acc11 = {};

  int r8 = t >> 2, c8 = (t & 3) * 8;   // row 0..63, k-offset {0,8,16,24}

  const uint32_t* aBase = Abf + ((size_t)(mt * 64 + r8) * DV + kt * 512 + c8) / 2;
  const uint32_t* bBase = W1T + ((size_t)(nt * 64 + r8) * DV + kt * 512 + c8) / 2;

  u32x4 av = *(const u32x4*)aBase;
  u32x4 bv = *(const u32x4*)bBase;

  for (int it = 0; it < 16; ++it){
    __syncthreads();   // previous iteration's frag reads done
    *(u32x4*)&Als[r8 * 40 + c8] = av;
    *(u32x4*)&Bls[r8 * 40 + c8] = bv;
    if (it < 15){      // prefetch next k-slab while MFMA runs
      av = *(const u32x4*)(aBase + (it + 1) * 16);
      bv = *(const u32x4*)(bBase + (it + 1) * 16);
    }
    __syncthreads();

    s16x8 af0 = *(const s16x8*)&Als[(wm * 32 + col) * 40 + quad * 8];
    s16x8 af1 = *(const s16x8*)&Als[(wm * 32 + 16 + col) * 40 + quad * 8];
    s16x8 bf0 = *(const s16x8*)&Bls[(wn * 32 + col) * 40 + quad * 8];
    s16x8 bf1 = *(const s16x8*)&Bls[(wn * 32 + 16 + col) * 40 + quad * 8];

    acc00 = __builtin_amdgcn_mfma_f32_16x16x32_bf16(af0, bf0, acc00, 0, 0, 0);
    acc01 = __builtin_amdgcn_mfma_f32_16x16x32_bf16(af0, bf1, acc01, 0, 0, 0);
    acc10 = __builtin_amdgcn_mfma_f32_16x16x32_bf16(af1, bf0, acc10, 0, 0, 0);
    acc11 = __builtin_amdgcn_mfma_f32_16x16x32_bf16(af1, bf1, acc11, 0, 0, 0);
  }

  int rbase = mt * 64 + wm * 32 + quad * 4;
  int cbase = nt * 64 + wn * 32 + col;
  #pragma unroll
  for (int r = 0; r < 4; ++r){
    atomicAdd(&H[(size_t)(rbase + r) * DH + cbase],           acc00[r]);
    atomicAdd(&H[(size_t)(rbase + r) * DH + cbase + 16],      acc01[r]);
    atomicAdd(&H[(size_t)(rbase + 16 + r) * DH + cbase],      acc10[r]);
    atomicAdd(&H[(size_t)(rbase + 16 + r) * DH + cbase + 16], acc11[r]);
  }
}

// ---------------------------------------------------------------------------
// Kernel 3: E2 = pack_f16( relu(H + b1) @ W2 + b2 )  [256][50] half2
// matvec: 256 blocks (1 per row); W2T L2-resident; hs reads wave-uniform
// ---------------------------------------------------------------------------
__global__ __launch_bounds__(256) void gemm2(const float* __restrict__ H,
                                             const float* __restrict__ b1,
                                             const float* __restrict__ W2T,
                                             const float* __restrict__ b2,
                                             uint32_t* __restrict__ E2){
  __shared__ float hs[DH];
  __shared__ float red[4][64][2];
  int t = threadIdx.x;
  int n = blockIdx.x;

  f32x4 hv = *(const f32x4*)&H[(size_t)n * DH + t * 4];
  f32x4 bv = *(const f32x4*)&b1[t * 4];
  f32x4 hr;
  #pragma unroll
  for (int i = 0; i < 4; ++i) hr[i] = __builtin_fmaxf(hv[i] + bv[i], 0.f);
  *(f32x4*)&hs[t * 4] = hr;
  __syncthreads();

  int d2 = t & 63, ks = t >> 6;      // wave = one ks slice -> uniform hs reads
  float a00 = 0.f, a01 = 0.f, a10 = 0.f, a11 = 0.f;
  if (d2 < 50){
    const float* w0 = W2T + (size_t)(2 * d2) * DH + ks * 256;
    const float* w1 = w0 + DH;
    const float* hp = hs + ks * 256;
    #pragma unroll 4
    for (int kk = 0; kk < 256; kk += 8){
      f32x4 h0 = *(const f32x4*)(hp + kk);
      f32x4 h1 = *(const f32x4*)(hp + kk + 4);
      f32x4 wa = *(const f32x4*)(w0 + kk);
      f32x4 wb = *(const f32x4*)(w0 + kk + 4);
      f32x4 wc = *(const f32x4*)(w1 + kk);
      f32x4 wd = *(const f32x4*)(w1 + kk + 4);
      #pragma unroll
      for (int i = 0; i < 4; ++i){
        a00 = __builtin_fmaf(wa[i], h0[i], a00);
        a01 = __builtin_fmaf(wb[i], h1[i], a01);
        a10 = __builtin_fmaf(wc[i], h0[i], a10);
        a11 = __builtin_fmaf(wd[i], h1[i], a11);
      }
    }
  }
  red[ks][d2][0] = a00 + a01;
  red[ks][d2][1] = a10 + a11;
  __syncthreads();
  if (t < 50){
    float s0 = red[0][t][0] + red[1][t][0] + red[2][t][0] + red[3][t][0] + b2[2 * t];
    float s1 = red[0][t][1] + red[1][t][1] + red[2][t][1] + red[3][t][1] + b2[2 * t + 1];
    E2[(size_t)n * 50 + t] =
        __builtin_bit_cast(uint32_t, __builtin_amdgcn_cvt_pkrtz(s0, s1));
  }
}

// ---------------------------------------------------------------------------
// Kernel 4: scores[n][l] = -sqrt( sum_d relu(lv[l][d] - e[n][d])^2 )
// grid = (79 l-tiles, 8 n-tiles of 32), 256 thr; lv cached in 50 VGPRs,
// reused for 32 n-rows -> lvT traffic halved vs 16-row tiles
// ---------------------------------------------------------------------------
__global__ __launch_bounds__(256) void scores_k(const uint32_t* __restrict__ lvT,
                                                const uint32_t* __restrict__ E2,
                                                float* __restrict__ out){
  int t = threadIdx.x;
  int l = blockIdx.x * 256 + t;
  int n0 = blockIdx.y * 32;
  bool lok = l < LTOT;

  f16x2 lv[50];
  #pragma unroll
  for (int d2 = 0; d2 < 50; ++d2)
    lv[d2] = __builtin_bit_cast(f16x2, lvT[(size_t)d2 * LPAD + l]);

  f16x2 z = {(_Float16)0, (_Float16)0};
  float* op = out + (size_t)n0 * LTOT + l;
  #pragma unroll 1
  for (int i = 0; i < 32; ++i){
    const uint32_t* er = E2 + (size_t)(n0 + i) * 50;   // block-uniform -> s_load
    float acc0 = 0.f, acc1 = 0.f;
    #pragma unroll
    for (int d2 = 0; d2 < 50; d2 += 2){
      f16x2 ev0 = __builtin_bit_cast(f16x2, er[d2]);
      f16x2 ev1 = __builtin_bit_cast(f16x2, er[d2 + 1]);
      f16x2 df0 = lv[d2] - ev0;
      f16x2 df1 = lv[d2 + 1] - ev1;
      df0 = __builtin_elementwise_max(df0, z);
      df1 = __builtin_elementwise_max(df1, z);
      acc0 = dot2acc(df0, acc0);
      acc1 = dot2acc(df1, acc1);
    }
    if (lok) op[(size_t)i * LTOT] = -__builtin_sqrtf(acc0 + acc1);
  }
}

// ---------------------------------------------------------------------------
extern "C" void kernel_launch(void* const* d_in, const int* in_sizes, int n_in,
                              void* d_out, int out_size, void* d_ws, size_t ws_size,
                              hipStream_t stream){
  const float* vfs = (const float*)d_in[0];
  const float* lab = (const float*)d_in[1];
  const float* W1  = (const float*)d_in[2];
  const float* b1  = (const float*)d_in[3];
  const float* W2  = (const float*)d_in[4];
  const float* b2  = (const float*)d_in[5];
  float* out = (float*)d_out;

  char* ws = (char*)d_ws;
  uint32_t* lvT = (uint32_t*)ws;                    // 4,044,800 B
  float*    H   = (float*)(ws + 4044800);           // 1,048,576 B
  uint32_t* E2  = (uint32_t*)(ws + 5093376);        //    51,200 B
  float*    W2T = (float*)(ws + 5144576);           //   409,600 B
  uint32_t* Abf = (uint32_t*)(ws + 5554176);        // 2,097,152 B (bf16 pairs)
  uint32_t* W1T = (uint32_t*)(ws + 7651328);        // 8,388,608 B (bf16 pairs)

  prep_k<<<490, 256, 0, stream>>>(lab, lvT, W2, W2T, H, vfs, Abf, W1, W1T);
  gemm1<<<512, 256, 0, stream>>>(Abf, W1T, H);
  gemm2<<<256, 256, 0, stream>>>(H, b1, W2T, b2, E2);
  scores_k<<<dim3(79, 8), 256, 0, stream>>>(lvT, E2, out);
}

// Round 6
// 156.459 us; speedup vs baseline: 1.1347x; 1.1347x over previous
//
#include <hip/hip_runtime.h>
#include <stdint.h>

#define LTOT 20000
#define LPAD 20224   // 158*128 = 79*256
#define DV   4096
#define DH   1024
#define DE   100
#define NB   256

using f32x4 = __attribute__((ext_vector_type(4))) float;
using s16x8 = __attribute__((ext_vector_type(8))) short;
using u32x2 = __attribute__((ext_vector_type(2))) uint32_t;
using u32x4 = __attribute__((ext_vector_type(4))) uint32_t;
using f16x2 = __attribute__((ext_vector_type(2))) _Float16;

static __device__ __forceinline__ short f2bf(float x){
  union{float f; uint32_t u;} v; v.f = x;
  uint32_t r = (v.u + 0x7fffu + ((v.u >> 16) & 1u)) >> 16;
  return (short)r;
}

// pack two f32 -> two bf16 (RTNE)
static __device__ __forceinline__ uint32_t pack2bf(float x, float y){
#if __has_builtin(__builtin_amdgcn_cvt_pk_bf16_f32)
  return __builtin_bit_cast(uint32_t, __builtin_amdgcn_cvt_pk_bf16_f32(x, y));
#else
  return (uint32_t)(uint16_t)f2bf(x) | ((uint32_t)(uint16_t)f2bf(y) << 16);
#endif
}

static __device__ __forceinline__ float dot2acc(f16x2 a, float c){
#if __has_builtin(__builtin_amdgcn_fdot2)
  return __builtin_amdgcn_fdot2(a, a, c, false);
#else
  float x = (float)a[0], y = (float)a[1];
  return __builtin_fmaf(x, x, __builtin_fmaf(y, y, c));
#endif
}

// ---------------------------------------------------------------------------
// Kernel 1 (prep), block ranges:
//   0..157  : label_vecs [20000][100] f32 -> lvT [50][LPAD] half2
//   158..165: W2 [1024][100] -> W2T [100][1024] f32
//   166..169: zero H (1 MB)
//   170..233: Abf = bf16(relu(vfs)) [256][4096]
//   234..489: W1 [4096][1024] f32 -> W1T [1024][4096] bf16 (128x128 LDS tiles)
// ---------------------------------------------------------------------------
__global__ __launch_bounds__(256) void prep_k(const float* __restrict__ lab,
                                              uint32_t* __restrict__ lvT,
                                              const float* __restrict__ W2,
                                              float* __restrict__ W2T,
                                              float* __restrict__ H,
                                              const float* __restrict__ vfs,
                                              uint32_t* __restrict__ Abf,
                                              const float* __restrict__ W1,
                                              uint32_t* __restrict__ W1T){
  __shared__ __align__(16) char smem[128 * 101 * 4];   // 51.7 KB, multi-use
  float* T = (float*)smem;
  short* Ts = (short*)smem;                            // [128][136] for W1T tiles
  int t = threadIdx.x;
  int bx = blockIdx.x;
  if (bx < 158){
    int lbase = bx * 128;
    for (int i = t; i < 128 * 100; i += 256){
      int lloc = i / 100;
      int d = i - lloc * 100;
      int l = lbase + lloc;
      float v = (l < LTOT) ? lab[(size_t)l * DE + d] : 0.f;
      T[lloc * 101 + d] = v;
    }
    __syncthreads();
    int lloc = t & 127;
    int half = t >> 7;
    uint32_t lg = (uint32_t)(lbase + lloc);
    #pragma unroll
    for (int q = 0; q < 25; ++q){
      int d2 = half * 25 + q;
      f16x2 p;
      p[0] = (_Float16)T[lloc * 101 + 2 * d2];
      p[1] = (_Float16)T[lloc * 101 + 2 * d2 + 1];
      lvT[(size_t)d2 * LPAD + lg] = __builtin_bit_cast(uint32_t, p);
    }
  } else if (bx < 166){
    int k0 = (bx - 158) * 128;
    for (int i = t; i < 128 * 100; i += 256){
      int kk = i / 100;
      int d = i - kk * 100;
      T[kk * 101 + d] = W2[(size_t)(k0 + kk) * DE + d];
    }
    __syncthreads();
    for (int i = t; i < 100 * 128; i += 256){
      int d = i >> 7, kk = i & 127;
      W2T[(size_t)d * DH + k0 + kk] = T[kk * 101 + d];
    }
  } else if (bx < 170){
    f32x4 z = {};
    float* p = H + (size_t)(bx - 166) * 65536 + t * 4;
    #pragma unroll 4
    for (int i = 0; i < 64; ++i) *(f32x4*)(p + i * 1024) = z;
  } else if (bx < 234){
    // vfs -> bf16(relu): 64 blocks x 16384 floats
    size_t base = (size_t)(bx - 170) * 16384;
    #pragma unroll 4
    for (int j = 0; j < 16; ++j){
      size_t idx = base + (size_t)(j * 256 + t) * 4;
      f32x4 v = *(const f32x4*)(vfs + idx);
      u32x2 o;
      o[0] = pack2bf(__builtin_fmaxf(v[0], 0.f), __builtin_fmaxf(v[1], 0.f));
      o[1] = pack2bf(__builtin_fmaxf(v[2], 0.f), __builtin_fmaxf(v[3], 0.f));
      *(u32x2*)(Abf + (idx >> 1)) = o;
    }
  } else {
    // W1T bf16 transpose: 256 blocks, tile 128k x 128n; Ts[n][k] pad 136
    int bi = bx - 234;
    int k0 = (bi >> 3) * 128, n0 = (bi & 7) * 128;
    #pragma unroll 4
    for (int j = 0; j < 16; ++j){
      int lin = j * 256 + t;              // 4096 f32x4 slots = 128 rows x 32
      int row = lin >> 5, c4 = lin & 31;
      f32x4 v = *(const f32x4*)(W1 + (size_t)(k0 + row) * DH + n0 + c4 * 4);
      #pragma unroll
      for (int i = 0; i < 4; ++i)
        Ts[(c4 * 4 + i) * 136 + row] = f2bf(v[i]);
    }
    __syncthreads();
    #pragma unroll
    for (int j = 0; j < 8; ++j){
      int lin = j * 256 + t;              // 2048 16B-chunks = 128 n x 16
      int nn = lin >> 4, c8 = lin & 15;
      u32x4 o = *(const u32x4*)&Ts[nn * 136 + c8 * 8];
      *(u32x4*)(W1T + ((size_t)(n0 + nn) * DV + k0 + c8 * 8) / 2) = o;
    }
  }
}

// ---------------------------------------------------------------------------
// Kernel 2: H += Abf @ W1T^T  (bf16 MFMA, 64x64 tiles, split-K=8, atomics)
// grid = 4(mt)*16(nt)*8(kt) = 512 blocks (2/CU), 256 thr; pure-copy staging
// ---------------------------------------------------------------------------
__global__ __launch_bounds__(256) void gemm1(const uint32_t* __restrict__ Abf,
                                             const uint32_t* __restrict__ W1T,
                                             float* __restrict__ H){
  __shared__ __align__(16) short Als[64 * 40];  // [m][k] bf16, pad 40
  __shared__ __align__(16) short Bls[64 * 40];  // [n][k] bf16, pad 40
  int t = threadIdx.x;
  int bx = blockIdx.x;
  int kt = bx & 7, nt = (bx >> 3) & 15, mt = bx >> 7;
  int lane = t & 63, wv = t >> 6;
  int wm = wv >> 1, wn = wv & 1;
  int col = lane & 15, quad = lane >> 4;

  f32x4 acc00 = {}, acc01 = {}, acc10 = {}, acc11 = {};

  int r8 = t >> 2, c8 = (t & 3) * 8;   // row 0..63, k-offset {0,8,16,24}

  const uint32_t* aBase = Abf + ((size_t)(mt * 64 + r8) * DV + kt * 512 + c8) / 2;
  const uint32_t* bBase = W1T + ((size_t)(nt * 64 + r8) * DV + kt * 512 + c8) / 2;

  u32x4 av = *(const u32x4*)aBase;
  u32x4 bv = *(const u32x4*)bBase;

  for (int it = 0; it < 16; ++it){
    __syncthreads();   // previous iteration's frag reads done
    *(u32x4*)&Als[r8 * 40 + c8] = av;
    *(u32x4*)&Bls[r8 * 40 + c8] = bv;
    if (it < 15){      // prefetch next k-slab while MFMA runs
      av = *(const u32x4*)(aBase + (it + 1) * 16);
      bv = *(const u32x4*)(bBase + (it + 1) * 16);
    }
    __syncthreads();

    s16x8 af0 = *(const s16x8*)&Als[(wm * 32 + col) * 40 + quad * 8];
    s16x8 af1 = *(const s16x8*)&Als[(wm * 32 + 16 + col) * 40 + quad * 8];
    s16x8 bf0 = *(const s16x8*)&Bls[(wn * 32 + col) * 40 + quad * 8];
    s16x8 bf1 = *(const s16x8*)&Bls[(wn * 32 + 16 + col) * 40 + quad * 8];

    acc00 = __builtin_amdgcn_mfma_f32_16x16x32_bf16(af0, bf0, acc00, 0, 0, 0);
    acc01 = __builtin_amdgcn_mfma_f32_16x16x32_bf16(af0, bf1, acc01, 0, 0, 0);
    acc10 = __builtin_amdgcn_mfma_f32_16x16x32_bf16(af1, bf0, acc10, 0, 0, 0);
    acc11 = __builtin_amdgcn_mfma_f32_16x16x32_bf16(af1, bf1, acc11, 0, 0, 0);
  }

  int rbase = mt * 64 + wm * 32 + quad * 4;
  int cbase = nt * 64 + wn * 32 + col;
  #pragma unroll
  for (int r = 0; r < 4; ++r){
    atomicAdd(&H[(size_t)(rbase + r) * DH + cbase],           acc00[r]);
    atomicAdd(&H[(size_t)(rbase + r) * DH + cbase + 16],      acc01[r]);
    atomicAdd(&H[(size_t)(rbase + 16 + r) * DH + cbase],      acc10[r]);
    atomicAdd(&H[(size_t)(rbase + 16 + r) * DH + cbase + 16], acc11[r]);
  }
}

// ---------------------------------------------------------------------------
// Kernel 3: E2T = pack_f16( relu(H + b1) @ W2 + b2 ) TRANSPOSED [50][256] half2
// matvec: 256 blocks (1 per row); W2T L2-resident; hs reads wave-uniform
// ---------------------------------------------------------------------------
__global__ __launch_bounds__(256) void gemm2(const float* __restrict__ H,
                                             const float* __restrict__ b1,
                                             const float* __restrict__ W2T,
                                             const float* __restrict__ b2,
                                             uint32_t* __restrict__ E2T){
  __shared__ float hs[DH];
  __shared__ float red[4][64][2];
  int t = threadIdx.x;
  int n = blockIdx.x;

  f32x4 hv = *(const f32x4*)&H[(size_t)n * DH + t * 4];
  f32x4 bv = *(const f32x4*)&b1[t * 4];
  f32x4 hr;
  #pragma unroll
  for (int i = 0; i < 4; ++i) hr[i] = __builtin_fmaxf(hv[i] + bv[i], 0.f);
  *(f32x4*)&hs[t * 4] = hr;
  __syncthreads();

  int d2 = t & 63, ks = t >> 6;      // wave = one ks slice -> uniform hs reads
  float a00 = 0.f, a01 = 0.f, a10 = 0.f, a11 = 0.f;
  if (d2 < 50){
    const float* w0 = W2T + (size_t)(2 * d2) * DH + ks * 256;
    const float* w1 = w0 + DH;
    const float* hp = hs + ks * 256;
    #pragma unroll 4
    for (int kk = 0; kk < 256; kk += 8){
      f32x4 h0 = *(const f32x4*)(hp + kk);
      f32x4 h1 = *(const f32x4*)(hp + kk + 4);
      f32x4 wa = *(const f32x4*)(w0 + kk);
      f32x4 wb = *(const f32x4*)(w0 + kk + 4);
      f32x4 wc = *(const f32x4*)(w1 + kk);
      f32x4 wd = *(const f32x4*)(w1 + kk + 4);
      #pragma unroll
      for (int i = 0; i < 4; ++i){
        a00 = __builtin_fmaf(wa[i], h0[i], a00);
        a01 = __builtin_fmaf(wb[i], h1[i], a01);
        a10 = __builtin_fmaf(wc[i], h0[i], a10);
        a11 = __builtin_fmaf(wd[i], h1[i], a11);
      }
    }
  }
  red[ks][d2][0] = a00 + a01;
  red[ks][d2][1] = a10 + a11;
  __syncthreads();
  if (t < 50){
    float s0 = red[0][t][0] + red[1][t][0] + red[2][t][0] + red[3][t][0] + b2[2 * t];
    float s1 = red[0][t][1] + red[1][t][1] + red[2][t][1] + red[3][t][1] + b2[2 * t + 1];
    // transposed: E2T[d2][n] so scores_k reads 16 consecutive n per s_load
    E2T[(size_t)t * NB + n] =
        __builtin_bit_cast(uint32_t, __builtin_amdgcn_cvt_pkrtz(s0, s1));
  }
}

// ---------------------------------------------------------------------------
// Kernel 4: scores[n][l] = -sqrt( sum_d relu(lv[l][d] - e[n][d])^2 )
// grid = (79 l-tiles, 16 n-tiles), 256 thr; d2 OUTER loop, 16 fp32 acc in regs.
// Per d2: 1 coalesced lv load + s_load_dwordx16 of E2T row + 48 VALU into 16
// independent chains. No long-lived register array -> no remat problem (r5:
// VGPR=36 proved lv[50] was reloaded from global every n-iteration).
// ---------------------------------------------------------------------------
__global__ __launch_bounds__(256) void scores_k(const uint32_t* __restrict__ lvT,
                                                const uint32_t* __restrict__ E2T,
                                                float* __restrict__ out){
  int t = threadIdx.x;
  int l = blockIdx.x * 256 + t;
  int n0 = blockIdx.y * 16;

  float acc[16];
  #pragma unroll
  for (int i = 0; i < 16; ++i) acc[i] = 0.f;

  f16x2 z = {(_Float16)0, (_Float16)0};
  const uint32_t* lp = lvT + l;
  const uint32_t* ep = E2T + n0;          // block-uniform

  #pragma unroll 2
  for (int d2 = 0; d2 < 50; ++d2){
    f16x2 lv = __builtin_bit_cast(f16x2, lp[(size_t)d2 * LPAD]);
    #pragma unroll
    for (int i = 0; i < 16; ++i){
      f16x2 ev = __builtin_bit_cast(f16x2, ep[(size_t)d2 * NB + i]);  // s_load
      f16x2 df = lv - ev;
      df = __builtin_elementwise_max(df, z);
      acc[i] = dot2acc(df, acc[i]);
    }
  }

  if (l < LTOT){
    float* op = out + (size_t)n0 * LTOT + l;
    #pragma unroll
    for (int i = 0; i < 16; ++i)
      op[(size_t)i * LTOT] = -__builtin_sqrtf(acc[i]);
  }
}

// ---------------------------------------------------------------------------
extern "C" void kernel_launch(void* const* d_in, const int* in_sizes, int n_in,
                              void* d_out, int out_size, void* d_ws, size_t ws_size,
                              hipStream_t stream){
  const float* vfs = (const float*)d_in[0];
  const float* lab = (const float*)d_in[1];
  const float* W1  = (const float*)d_in[2];
  const float* b1  = (const float*)d_in[3];
  const float* W2  = (const float*)d_in[4];
  const float* b2  = (const float*)d_in[5];
  float* out = (float*)d_out;

  char* ws = (char*)d_ws;
  uint32_t* lvT = (uint32_t*)ws;                    // 4,044,800 B
  float*    H   = (float*)(ws + 4044800);           // 1,048,576 B
  uint32_t* E2T = (uint32_t*)(ws + 5093376);        //    51,200 B  [50][256]
  float*    W2T = (float*)(ws + 5144576);           //   409,600 B
  uint32_t* Abf = (uint32_t*)(ws + 5554176);        // 2,097,152 B (bf16 pairs)
  uint32_t* W1T = (uint32_t*)(ws + 7651328);        // 8,388,608 B (bf16 pairs)

  prep_k<<<490, 256, 0, stream>>>(lab, lvT, W2, W2T, H, vfs, Abf, W1, W1T);
  gemm1<<<512, 256, 0, stream>>>(Abf, W1T, H);
  gemm2<<<256, 256, 0, stream>>>(H, b1, W2T, b2, E2T);
  scores_k<<<dim3(79, 16), 256, 0, stream>>>(lvT, E2T, out);
}